// Round 3
// baseline (9498.336 us; speedup 1.0000x reference)
//
#include <hip/hip_runtime.h>

// Stop implicit mul+add fusion: we emulate numpy f32 per-op rounding exactly.
#pragma clang fp contract(off)

typedef unsigned short u16;
typedef unsigned int u32;
typedef unsigned long long u64;

#define BB 512
#define CC 128
#define TT 500
#define NN 512

// ---------------- prep kernel ----------------
// Transposed recurrent/feedforward weights with a 513th all-zero row (index NN)
// used as the padding target so the sparse loop can run in groups of 8 without
// branches (adding 0.0f is exact, so pads don't perturb the f32 chain).
__global__ void prep_weights(const float* __restrict__ W2, const float* __restrict__ Wr2,
                             float* __restrict__ Wr2T, float* __restrict__ W2T) {
  int i = blockIdx.x * blockDim.x + threadIdx.x;
  if (i < 513 * 512) {
    int k = i >> 9, n = i & 511;
    Wr2T[i] = (k < NN) ? Wr2[n * NN + k] : 0.0f;
    W2T[i]  = (k < NN) ? W2[n * NN + k] : 0.0f;
  }
}

// ---------------- recurrent kernel ----------------

// f32 sum of weight rows selected by a compacted ASCENDING index list (padded
// to x8 with index NN -> zero row). Single sequential add chain in ascending
// index order == dense BLAS k-chain with 0/1 A-operand (fma(0,w,c)==c exactly).
__device__ __forceinline__ float sparse_sum_f32(const float* __restrict__ mat,
                                                const u16* list, int cnt, int n) {
  float s = 0.0f;
  for (int i = 0; i < cnt; i += 8) {
    uint4 q = *(const uint4*)(list + i);  // 8 u16 indices, broadcast LDS read
    int k0 = q.x & 0xffff, k1 = q.x >> 16;
    int k2 = q.y & 0xffff, k3 = q.y >> 16;
    int k4 = q.z & 0xffff, k5 = q.z >> 16;
    int k6 = q.w & 0xffff, k7 = q.w >> 16;
    float f0 = mat[k0 * NN + n];
    float f1 = mat[k1 * NN + n];
    float f2 = mat[k2 * NN + n];
    float f3 = mat[k3 * NN + n];
    float f4 = mat[k4 * NN + n];
    float f5 = mat[k5 * NN + n];
    float f6 = mat[k6 * NN + n];
    float f7 = mat[k7 * NN + n];
    // strict sequential order (no reassociation without fast-math)
    s += f0; s += f1; s += f2; s += f3;
    s += f4; s += f5; s += f6; s += f7;
  }
  return s;
}

extern "C" __global__ void __launch_bounds__(512, 2)
recur_kernel(const float* __restrict__ x, const float* __restrict__ W1,
             const float* __restrict__ Wr2T, const float* __restrict__ W2T,
             const float* __restrict__ W4,
             const float* __restrict__ b1, const float* __restrict__ b2,
             const float* __restrict__ br2, const float* __restrict__ b4,
             const float* __restrict__ Vth1, const float* __restrict__ tau1,
             const float* __restrict__ Vth2, const float* __restrict__ tau2,
             const float* __restrict__ tau_out, float* __restrict__ out) {
  const int n = threadIdx.x;   // neuron
  const int b = blockIdx.x;    // batch row
  const int lane = n & 63;
  const int wave = n >> 6;

  __shared__ float xs[CC];
  __shared__ u64 wordsA[8], wordsB[8];
  __shared__ __align__(16) u16 listA[2][528];  // 528 -> each sub-array 16B aligned
  __shared__ __align__(16) u16 listB[2][528];
  __shared__ int cA[2], cB[2];

  // W1 row of this neuron in registers
  float w1r[CC];
  {
    const float4* wp = (const float4*)(W1 + n * CC);
#pragma unroll
    for (int i = 0; i < CC / 4; ++i) {
      float4 q = wp[i];
      w1r[i * 4 + 0] = q.x;
      w1r[i * 4 + 1] = q.y;
      w1r[i * 4 + 2] = q.z;
      w1r[i * 4 + 3] = q.w;
    }
  }

  float mem1 = 0.0f, mem2 = 0.0f;
  const float b1v = b1[n], b2v = b2[n], br2v = br2[n];
  const float t1 = tau1[n], t2 = tau2[n];
  const float v1 = Vth1[n], v2 = Vth2[n];
  const float to0 = tau_out[0], to1 = tau_out[1];
  const float b40 = b4[0], b41 = b4[1];
  int sp1 = 0, sp2 = 0, sc1 = 0, sc2 = 0;
  float memo0 = 0.0f, memo1 = 0.0f;  // only thread 0's copy is used

  if (n == 0) { cA[0] = 0; cB[0] = 0; }

  for (int t = 0; t < TT; ++t) {
    const int pp = t & 1, qq = pp ^ 1;  // read parity / write parity
    // strided x read; lines are L1-resident across 16 consecutive t
    if (n < CC) xs[n] = x[(b * CC + n) * TT + t];
    __syncthreads();  // B0: xs ready; listA[pp]/listB[pp]/counts ready

    // ---- layer 1: i1 = (x@W1^T + b1) + (sp1@Wr2^T + br2) ----
    // BLAS sgemm: single FMA chain per output element, ascending k.
    float acc = 0.0f;
#pragma unroll
    for (int c = 0; c < CC; ++c) acc = __builtin_fmaf(xs[c], w1r[c], acc);
    float u1 = acc + b1v;                                    // matmul + b1
    float r1 = sparse_sum_f32(Wr2T, listA[pp], cA[pp], n);   // sp1@Wr2^T
    float w1s = r1 + br2v;                                   // + br2
    float i1 = u1 + w1s;
    float a1m = t1 * mem1;              // tau1*mem1 (rounded)
    a1m = sp1 ? 0.0f : a1m;             // *(1-sp1): exact (x*1 or 0)
    float m1 = a1m + i1;                // + i1 (rounded)
    mem1 = m1;
    const int s1 = (m1 - v1) > 0.0f ? 1 : 0;
    u64 ba = __ballot(s1 != 0);
    if (lane == 0) wordsA[wave] = ba;
    __syncthreads();  // B1: wordsA ready

    // build listA[qq] (current s1), ascending-n order
    {
      int tot = 0, base = 0;
#pragma unroll
      for (int j = 0; j < 8; ++j) {
        int pj = __popcll(wordsA[j]);
        if (j < wave) base += pj;
        tot += pj;
      }
      if (tot) {
        if (s1) {
          int pos = base + __popcll(wordsA[wave] & ((1ull << lane) - 1ull));
          listA[qq][pos] = (u16)n;
        }
        if (n < 8) listA[qq][tot + n] = (u16)NN;  // pad -> zero row
      }
      if (n == 0) cA[qq] = tot;
    }
    __syncthreads();  // B1b: listA[qq] ready

    // ---- layer 2: i2 = (s1@W2^T + b2) + (sp2@Wr2^T + br2) ----
    float ff = sparse_sum_f32(W2T, listA[qq], cA[qq], n);
    float u2 = ff + b2v;
    float r2 = sparse_sum_f32(Wr2T, listB[pp], cB[pp], n);
    float w2s = r2 + br2v;
    float i2 = u2 + w2s;
    float a2m = t2 * mem2;
    a2m = sp2 ? 0.0f : a2m;
    float m2 = a2m + i2;
    mem2 = m2;
    const int s2 = (m2 - v2) > 0.0f ? 1 : 0;
    u64 bb = __ballot(s2 != 0);
    if (lane == 0) wordsB[wave] = bb;
    sp1 = s1; sp2 = s2; sc1 += s1; sc2 += s2;
    __syncthreads();  // B2: wordsB ready

    // build listB[qq] (current s2) for next step's layer-2 recurrence
    {
      int tot = 0, base = 0;
#pragma unroll
      for (int j = 0; j < 8; ++j) {
        int pj = __popcll(wordsB[j]);
        if (j < wave) base += pj;
        tot += pj;
      }
      if (tot) {
        if (s2) {
          int pos = base + __popcll(wordsB[wave] & ((1ull << lane) - 1ull));
          listB[qq][pos] = (u16)n;
        }
        if (n < 8) listB[qq][tot + n] = (u16)NN;
      }
      if (n == 0) cB[qq] = tot;
    }

    // ---- readout: memo = (tau_out*memo) + ((s2@W4^T) + b4) ----
    if (n == 0) {
      float a0 = 0.0f, a1 = 0.0f;  // ascending-k f32 chains
#pragma unroll
      for (int w = 0; w < 8; ++w) {
        u64 m = wordsB[w];
        while (m) {
          int k = (w << 6) + __builtin_ctzll(m);
          m &= m - 1ull;
          a0 += W4[k];
          a1 += W4[NN + k];
        }
      }
      float z0 = to0 * memo0;
      float z1 = to1 * memo1;
      memo0 = z0 + (a0 + b40);
      memo1 = z1 + (a1 + b41);
      out[(b * 2 + 0) * TT + t] = memo0;
      out[(b * 2 + 1) * TT + t] = memo1;
    }
    // next iteration's B0 orders these writes before any reuse
  }

  // spike-count outputs: sc/T (f32 divide, matches numpy f32 /int semantics)
  out[BB * 2 * TT + b * NN + n]           = (float)sc1 / 500.0f;
  out[BB * 2 * TT + BB * NN + b * NN + n] = (float)sc2 / 500.0f;
}

// ---------------- launcher ----------------

extern "C" void kernel_launch(void* const* d_in, const int* in_sizes, int n_in,
                              void* d_out, int out_size, void* d_ws, size_t ws_size,
                              hipStream_t stream) {
  (void)in_sizes; (void)n_in; (void)out_size; (void)ws_size;
  const float* x    = (const float*)d_in[0];
  const float* W1   = (const float*)d_in[1];
  const float* b1   = (const float*)d_in[2];
  const float* W2   = (const float*)d_in[3];
  const float* b2   = (const float*)d_in[4];
  const float* Wr2  = (const float*)d_in[5];
  const float* br2  = (const float*)d_in[6];
  // d_in[7..10] = W3,b3,Wr3,br3: dead code w.r.t. outputs — skipped
  const float* W4   = (const float*)d_in[11];
  const float* b4   = (const float*)d_in[12];
  const float* Vth1 = (const float*)d_in[13];
  const float* tau1 = (const float*)d_in[14];
  const float* Vth2 = (const float*)d_in[15];
  const float* tau2 = (const float*)d_in[16];
  // d_in[17..18] = Vth3,tau3: dead
  const float* tau_out = (const float*)d_in[19];

  // workspace layout (~2.1 MB total)
  char* ws = (char*)d_ws;
  float* Wr2T = (float*)ws;                 // 513*512*4 = 1,050,624 B
  float* W2T  = (float*)(ws + 1050624);     // 1,050,624 B

  hipLaunchKernelGGL(prep_weights, dim3((513 * 512 + 255) / 256), dim3(256), 0, stream,
                     W2, Wr2, Wr2T, W2T);
  hipLaunchKernelGGL(recur_kernel, dim3(BB), dim3(512), 0, stream,
                     x, W1, Wr2T, W2T, W4, b1, b2, br2, b4,
                     Vth1, tau1, Vth2, tau2, tau_out, (float*)d_out);
}

// Round 4
// 9470.831 us; speedup vs baseline: 1.0029x; 1.0029x over previous
//
#include <hip/hip_runtime.h>

// Emulate numpy f32 per-op rounding exactly: no implicit mul+add fusion.
#pragma clang fp contract(off)

typedef unsigned short u16;
typedef unsigned int u32;
typedef unsigned long long u64;

#define BB 512
#define CC 128
#define TT 500
#define NN 512

#define WS_I1FF 524288000ull          // 512*500*512*4
#define WS_TBL  1050624ull            // 513*512*4
#define WS_NEED (WS_I1FF + 2ull * WS_TBL)

// ---------------- prep kernel ----------------
// Transposed recurrent/feedforward weights with a 513th all-zero row (index NN)
// used as the padding target so the sparse loop can run in groups of 8 without
// branches (adding 0.0f is exact, so pads don't perturb the f32 chain).
__global__ void prep_weights(const float* __restrict__ W2, const float* __restrict__ Wr2,
                             float* __restrict__ Wr2T, float* __restrict__ W2T) {
  int i = blockIdx.x * blockDim.x + threadIdx.x;
  if (i < 513 * 512) {
    int k = i >> 9, n = i & 511;
    Wr2T[i] = (k < NN) ? Wr2[n * NN + k] : 0.0f;
    W2T[i]  = (k < NN) ? W2[n * NN + k] : 0.0f;
  }
}

// ---------------- i1ff GEMM: i1ff[b][t][n] = sum_c x[b][c][t]*W1[n][c] ----------------
// Bit-exact: each output is ONE ascending-c fmaf chain (same as round-3 GEMV).
// Block: 128 threads; thread owns 4 n (stride 128) x 16 tt accumulators.
#define T_TILE 16
#define CP 8           // c-panel size
#define W1L_PITCH 9    // pad 8 -> 9 floats to break bank alignment

__global__ void __launch_bounds__(128, 3)
gemm_i1ff(const float* __restrict__ x, const float* __restrict__ W1,
          float* __restrict__ i1ff) {
  const int b = blockIdx.x;
  const int tile = blockIdx.y;
  const int t0 = tile * T_TILE;
  const int tid = threadIdx.x;   // 0..127 = tn

  __shared__ float xs[CC * T_TILE];          // [c][tt], 8 KB
  __shared__ float W1L[NN * W1L_PITCH];      // [n][cc panel], 18 KB

  // load x tile (scalar, guarded for tail tile)
  for (int i = tid; i < CC * T_TILE; i += 128) {
    int c = i >> 4, tt = i & 15;
    int t = t0 + tt;
    xs[c * T_TILE + tt] = (t < TT) ? x[(b * CC + c) * TT + t] : 0.0f;
  }

  float acc[4][T_TILE];
#pragma unroll
  for (int r = 0; r < 4; ++r)
#pragma unroll
    for (int j = 0; j < T_TILE; ++j) acc[r][j] = 0.0f;

  for (int cp = 0; cp < CC / CP; ++cp) {
    __syncthreads();  // protect previous panel reads (and xs store at cp==0)
    // stage W1 panel: W1L[n][cc] = W1[n][cp*CP+cc]
    for (int i = tid; i < NN * CP; i += 128) {
      int n = i >> 3, cc = i & 7;
      W1L[n * W1L_PITCH + cc] = W1[n * CC + cp * CP + cc];
    }
    __syncthreads();
#pragma unroll
    for (int cc = 0; cc < CP; ++cc) {
      const int c = cp * CP + cc;
      float w0 = W1L[(tid + 0)   * W1L_PITCH + cc];
      float w1 = W1L[(tid + 128) * W1L_PITCH + cc];
      float w2 = W1L[(tid + 256) * W1L_PITCH + cc];
      float w3 = W1L[(tid + 384) * W1L_PITCH + cc];
#pragma unroll
      for (int j = 0; j < T_TILE; ++j) {
        float xv = xs[c * T_TILE + j];  // broadcast; contiguous -> b128
        acc[0][j] = __builtin_fmaf(xv, w0, acc[0][j]);
        acc[1][j] = __builtin_fmaf(xv, w1, acc[1][j]);
        acc[2][j] = __builtin_fmaf(xv, w2, acc[2][j]);
        acc[3][j] = __builtin_fmaf(xv, w3, acc[3][j]);
      }
    }
  }

  // store (coalesced over tid per (r,j))
#pragma unroll
  for (int j = 0; j < T_TILE; ++j) {
    int t = t0 + j;
    if (t < TT) {
      float* o = i1ff + ((size_t)b * TT + t) * NN;
#pragma unroll
      for (int r = 0; r < 4; ++r) o[tid + 128 * r] = acc[r][j];
    }
  }
}

// ---------------- sparse row-sum helpers ----------------
// f32 sum of weight rows selected by a compacted ASCENDING index list (padded
// to x8 with index NN -> zero row). Strict sequential add order == BLAS dense
// k-chain with 0/1 A-operand. Preloads up to 6 groups (48 loads in flight) so
// the L2 latency is paid once, not per group.
__device__ __forceinline__ float sparse_sum_pre(const float* __restrict__ mat,
                                                const u16* list, int cnt, int n) {
  if (cnt <= 0) return 0.0f;
  const int ng = (cnt + 7) >> 3;
  const int npre = ng < 6 ? ng : 6;
  float buf[48];
#pragma unroll
  for (int g = 0; g < 6; ++g) {
    if (g < npre) {
      uint4 q = *(const uint4*)(list + g * 8);
      buf[g * 8 + 0] = mat[(q.x & 0xffff) * NN + n];
      buf[g * 8 + 1] = mat[(q.x >> 16) * NN + n];
      buf[g * 8 + 2] = mat[(q.y & 0xffff) * NN + n];
      buf[g * 8 + 3] = mat[(q.y >> 16) * NN + n];
      buf[g * 8 + 4] = mat[(q.z & 0xffff) * NN + n];
      buf[g * 8 + 5] = mat[(q.z >> 16) * NN + n];
      buf[g * 8 + 6] = mat[(q.w & 0xffff) * NN + n];
      buf[g * 8 + 7] = mat[(q.w >> 16) * NN + n];
    }
  }
  float s = 0.0f;
#pragma unroll
  for (int g = 0; g < 6; ++g) {
    if (g < npre) {
#pragma unroll
      for (int j = 0; j < 8; ++j) s += buf[g * 8 + j];
    }
  }
  // rare tail (cnt > 48)
  for (int i = 48; i < cnt; i += 8) {
    uint4 q = *(const uint4*)(list + i);
    float f0 = mat[(q.x & 0xffff) * NN + n];
    float f1 = mat[(q.x >> 16) * NN + n];
    float f2 = mat[(q.y & 0xffff) * NN + n];
    float f3 = mat[(q.y >> 16) * NN + n];
    float f4 = mat[(q.z & 0xffff) * NN + n];
    float f5 = mat[(q.z >> 16) * NN + n];
    float f6 = mat[(q.w & 0xffff) * NN + n];
    float f7 = mat[(q.w >> 16) * NN + n];
    s += f0; s += f1; s += f2; s += f3;
    s += f4; s += f5; s += f6; s += f7;
  }
  return s;
}

// ---------------- recurrent kernel (main path: i1ff precomputed) ----------------

extern "C" __global__ void __launch_bounds__(512, 2)
recur2(const float* __restrict__ i1ff,
       const float* __restrict__ Wr2T, const float* __restrict__ W2T,
       const float* __restrict__ W4,
       const float* __restrict__ b1, const float* __restrict__ b2,
       const float* __restrict__ br2, const float* __restrict__ b4,
       const float* __restrict__ Vth1, const float* __restrict__ tau1,
       const float* __restrict__ Vth2, const float* __restrict__ tau2,
       const float* __restrict__ tau_out, float* __restrict__ out) {
  const int n = threadIdx.x;   // neuron
  const int b = blockIdx.x;    // batch row
  const int lane = n & 63;
  const int wave = n >> 6;

  __shared__ u64 wordsA[8], wordsB[8];
  __shared__ __align__(16) u16 listA[2][528];
  __shared__ __align__(16) u16 listB[2][528];
  __shared__ int cA[2], cB[2];

  float mem1 = 0.0f, mem2 = 0.0f;
  const float b1v = b1[n], b2v = b2[n], br2v = br2[n];
  const float t1 = tau1[n], t2 = tau2[n];
  const float v1 = Vth1[n], v2 = Vth2[n];
  const float to0 = tau_out[0], to1 = tau_out[1];
  const float b40 = b4[0], b41 = b4[1];
  int sp1 = 0, sp2 = 0, sc1 = 0, sc2 = 0;
  float memo0 = 0.0f, memo1 = 0.0f;  // only thread 0's copy is used

  if (n == 0) { cA[0] = 0; cB[0] = 0; }

  const float* ffp = i1ff + (size_t)b * TT * NN + n;
  float ffcur = ffp[0];

  for (int t = 0; t < TT; ++t) {
    const int pp = t & 1, qq = pp ^ 1;  // read parity / write parity
    // prefetch next step's feedforward value (no state dependence)
    const int tnext = (t + 1 < TT) ? (t + 1) : (TT - 1);
    float ffnext = ffp[(size_t)tnext * NN];
    __syncthreads();  // B0: prev-step lists/counts ready

    // ---- layer 1: i1 = (x@W1^T + b1) + (sp1@Wr2^T + br2) ----
    float r1 = sparse_sum_pre(Wr2T, listA[pp], cA[pp], n);
    float u1 = ffcur + b1v;
    float w1s = r1 + br2v;
    float i1 = u1 + w1s;
    float a1m = t1 * mem1;
    a1m = sp1 ? 0.0f : a1m;
    float m1 = a1m + i1;
    mem1 = m1;
    const int s1 = (m1 - v1) > 0.0f ? 1 : 0;
    u64 ba = __ballot(s1 != 0);
    if (lane == 0) wordsA[wave] = ba;
    __syncthreads();  // B1: wordsA ready

    // build listA[qq] (current s1), ascending-n order
    {
      int tot = 0, base = 0;
#pragma unroll
      for (int j = 0; j < 8; ++j) {
        int pj = __popcll(wordsA[j]);
        if (j < wave) base += pj;
        tot += pj;
      }
      if (tot) {
        if (s1) {
          int pos = base + __popcll(wordsA[wave] & ((1ull << lane) - 1ull));
          listA[qq][pos] = (u16)n;
        }
        if (n < 8) listA[qq][tot + n] = (u16)NN;  // pad -> zero row
      }
      if (n == 0) cA[qq] = tot;
    }
    __syncthreads();  // B1b: listA[qq] ready

    // ---- layer 2: i2 = (s1@W2^T + b2) + (sp2@Wr2^T + br2) ----
    float ff = sparse_sum_pre(W2T, listA[qq], cA[qq], n);
    float u2 = ff + b2v;
    float r2 = sparse_sum_pre(Wr2T, listB[pp], cB[pp], n);
    float w2s = r2 + br2v;
    float i2 = u2 + w2s;
    float a2m = t2 * mem2;
    a2m = sp2 ? 0.0f : a2m;
    float m2 = a2m + i2;
    mem2 = m2;
    const int s2 = (m2 - v2) > 0.0f ? 1 : 0;
    u64 bb = __ballot(s2 != 0);
    if (lane == 0) wordsB[wave] = bb;
    sp1 = s1; sp2 = s2; sc1 += s1; sc2 += s2;
    ffcur = ffnext;
    __syncthreads();  // B2: wordsB ready

    // build listB[qq] (current s2) for next step's layer-2 recurrence
    {
      int tot = 0, base = 0;
#pragma unroll
      for (int j = 0; j < 8; ++j) {
        int pj = __popcll(wordsB[j]);
        if (j < wave) base += pj;
        tot += pj;
      }
      if (tot) {
        if (s2) {
          int pos = base + __popcll(wordsB[wave] & ((1ull << lane) - 1ull));
          listB[qq][pos] = (u16)n;
        }
        if (n < 8) listB[qq][tot + n] = (u16)NN;
      }
      if (n == 0) cB[qq] = tot;
    }

    // ---- readout: memo = (tau_out*memo) + ((s2@W4^T) + b4) ----
    if (n == 0) {
      float a0 = 0.0f, a1 = 0.0f;  // ascending-k f32 chains
#pragma unroll
      for (int w = 0; w < 8; ++w) {
        u64 m = wordsB[w];
        while (m) {
          int k = (w << 6) + __builtin_ctzll(m);
          m &= m - 1ull;
          a0 += W4[k];
          a1 += W4[NN + k];
        }
      }
      float z0 = to0 * memo0;
      float z1 = to1 * memo1;
      memo0 = z0 + (a0 + b40);
      memo1 = z1 + (a1 + b41);
      out[(b * 2 + 0) * TT + t] = memo0;
      out[(b * 2 + 1) * TT + t] = memo1;
    }
  }

  out[BB * 2 * TT + b * NN + n]           = (float)sc1 / 500.0f;
  out[BB * 2 * TT + BB * NN + b * NN + n] = (float)sc2 / 500.0f;
}

// ---------------- fallback recurrent kernel (round-3, spill-fixed) ----------------

__device__ __forceinline__ float sparse_sum_f32(const float* __restrict__ mat,
                                                const u16* list, int cnt, int n) {
  float s = 0.0f;
  for (int i = 0; i < cnt; i += 8) {
    uint4 q = *(const uint4*)(list + i);
    int k0 = q.x & 0xffff, k1 = q.x >> 16;
    int k2 = q.y & 0xffff, k3 = q.y >> 16;
    int k4 = q.z & 0xffff, k5 = q.z >> 16;
    int k6 = q.w & 0xffff, k7 = q.w >> 16;
    float f0 = mat[k0 * NN + n];
    float f1 = mat[k1 * NN + n];
    float f2 = mat[k2 * NN + n];
    float f3 = mat[k3 * NN + n];
    float f4 = mat[k4 * NN + n];
    float f5 = mat[k5 * NN + n];
    float f6 = mat[k6 * NN + n];
    float f7 = mat[k7 * NN + n];
    s += f0; s += f1; s += f2; s += f3;
    s += f4; s += f5; s += f6; s += f7;
  }
  return s;
}

extern "C" __global__ void __launch_bounds__(512, 1)  // (512,1): allow VGPRs for w1r, no spill
recur_fb(const float* __restrict__ x, const float* __restrict__ W1,
         const float* __restrict__ Wr2T, const float* __restrict__ W2T,
         const float* __restrict__ W4,
         const float* __restrict__ b1, const float* __restrict__ b2,
         const float* __restrict__ br2, const float* __restrict__ b4,
         const float* __restrict__ Vth1, const float* __restrict__ tau1,
         const float* __restrict__ Vth2, const float* __restrict__ tau2,
         const float* __restrict__ tau_out, float* __restrict__ out) {
  const int n = threadIdx.x;
  const int b = blockIdx.x;
  const int lane = n & 63;
  const int wave = n >> 6;

  __shared__ float xs[CC];
  __shared__ u64 wordsA[8], wordsB[8];
  __shared__ __align__(16) u16 listA[2][528];
  __shared__ __align__(16) u16 listB[2][528];
  __shared__ int cA[2], cB[2];

  float w1r[CC];
  {
    const float4* wp = (const float4*)(W1 + n * CC);
#pragma unroll
    for (int i = 0; i < CC / 4; ++i) {
      float4 q = wp[i];
      w1r[i * 4 + 0] = q.x; w1r[i * 4 + 1] = q.y;
      w1r[i * 4 + 2] = q.z; w1r[i * 4 + 3] = q.w;
    }
  }

  float mem1 = 0.0f, mem2 = 0.0f;
  const float b1v = b1[n], b2v = b2[n], br2v = br2[n];
  const float t1 = tau1[n], t2 = tau2[n];
  const float v1 = Vth1[n], v2 = Vth2[n];
  const float to0 = tau_out[0], to1 = tau_out[1];
  const float b40 = b4[0], b41 = b4[1];
  int sp1 = 0, sp2 = 0, sc1 = 0, sc2 = 0;
  float memo0 = 0.0f, memo1 = 0.0f;

  if (n == 0) { cA[0] = 0; cB[0] = 0; }

  for (int t = 0; t < TT; ++t) {
    const int pp = t & 1, qq = pp ^ 1;
    if (n < CC) xs[n] = x[(b * CC + n) * TT + t];
    __syncthreads();

    float acc = 0.0f;
#pragma unroll
    for (int c = 0; c < CC; ++c) acc = __builtin_fmaf(xs[c], w1r[c], acc);
    float u1 = acc + b1v;
    float r1 = sparse_sum_f32(Wr2T, listA[pp], cA[pp], n);
    float w1s = r1 + br2v;
    float i1 = u1 + w1s;
    float a1m = t1 * mem1;
    a1m = sp1 ? 0.0f : a1m;
    float m1 = a1m + i1;
    mem1 = m1;
    const int s1 = (m1 - v1) > 0.0f ? 1 : 0;
    u64 ba = __ballot(s1 != 0);
    if (lane == 0) wordsA[wave] = ba;
    __syncthreads();

    {
      int tot = 0, base = 0;
#pragma unroll
      for (int j = 0; j < 8; ++j) {
        int pj = __popcll(wordsA[j]);
        if (j < wave) base += pj;
        tot += pj;
      }
      if (tot) {
        if (s1) {
          int pos = base + __popcll(wordsA[wave] & ((1ull << lane) - 1ull));
          listA[qq][pos] = (u16)n;
        }
        if (n < 8) listA[qq][tot + n] = (u16)NN;
      }
      if (n == 0) cA[qq] = tot;
    }
    __syncthreads();

    float ff = sparse_sum_f32(W2T, listA[qq], cA[qq], n);
    float u2 = ff + b2v;
    float r2 = sparse_sum_f32(Wr2T, listB[pp], cB[pp], n);
    float w2s = r2 + br2v;
    float i2 = u2 + w2s;
    float a2m = t2 * mem2;
    a2m = sp2 ? 0.0f : a2m;
    float m2 = a2m + i2;
    mem2 = m2;
    const int s2 = (m2 - v2) > 0.0f ? 1 : 0;
    u64 bb = __ballot(s2 != 0);
    if (lane == 0) wordsB[wave] = bb;
    sp1 = s1; sp2 = s2; sc1 += s1; sc2 += s2;
    __syncthreads();

    {
      int tot = 0, base = 0;
#pragma unroll
      for (int j = 0; j < 8; ++j) {
        int pj = __popcll(wordsB[j]);
        if (j < wave) base += pj;
        tot += pj;
      }
      if (tot) {
        if (s2) {
          int pos = base + __popcll(wordsB[wave] & ((1ull << lane) - 1ull));
          listB[qq][pos] = (u16)n;
        }
        if (n < 8) listB[qq][tot + n] = (u16)NN;
      }
      if (n == 0) cB[qq] = tot;
    }

    if (n == 0) {
      float a0 = 0.0f, a1 = 0.0f;
#pragma unroll
      for (int w = 0; w < 8; ++w) {
        u64 m = wordsB[w];
        while (m) {
          int k = (w << 6) + __builtin_ctzll(m);
          m &= m - 1ull;
          a0 += W4[k];
          a1 += W4[NN + k];
        }
      }
      float z0 = to0 * memo0;
      float z1 = to1 * memo1;
      memo0 = z0 + (a0 + b40);
      memo1 = z1 + (a1 + b41);
      out[(b * 2 + 0) * TT + t] = memo0;
      out[(b * 2 + 1) * TT + t] = memo1;
    }
  }

  out[BB * 2 * TT + b * NN + n]           = (float)sc1 / 500.0f;
  out[BB * 2 * TT + BB * NN + b * NN + n] = (float)sc2 / 500.0f;
}

// ---------------- launcher ----------------

extern "C" void kernel_launch(void* const* d_in, const int* in_sizes, int n_in,
                              void* d_out, int out_size, void* d_ws, size_t ws_size,
                              hipStream_t stream) {
  (void)in_sizes; (void)n_in; (void)out_size;
  const float* x    = (const float*)d_in[0];
  const float* W1   = (const float*)d_in[1];
  const float* b1   = (const float*)d_in[2];
  const float* W2   = (const float*)d_in[3];
  const float* b2   = (const float*)d_in[4];
  const float* Wr2  = (const float*)d_in[5];
  const float* br2  = (const float*)d_in[6];
  // d_in[7..10] = W3,b3,Wr3,br3: dead code w.r.t. outputs — skipped
  const float* W4   = (const float*)d_in[11];
  const float* b4   = (const float*)d_in[12];
  const float* Vth1 = (const float*)d_in[13];
  const float* tau1 = (const float*)d_in[14];
  const float* Vth2 = (const float*)d_in[15];
  const float* tau2 = (const float*)d_in[16];
  const float* tau_out = (const float*)d_in[19];

  char* ws = (char*)d_ws;

  if (ws_size >= WS_NEED) {
    float* i1ff = (float*)ws;                              // 524,288,000 B
    float* Wr2T = (float*)(ws + WS_I1FF);                  // 1,050,624 B
    float* W2T  = (float*)(ws + WS_I1FF + WS_TBL);         // 1,050,624 B

    hipLaunchKernelGGL(prep_weights, dim3((513 * 512 + 255) / 256), dim3(256), 0, stream,
                       W2, Wr2, Wr2T, W2T);
    hipLaunchKernelGGL(gemm_i1ff, dim3(BB, (TT + T_TILE - 1) / T_TILE), dim3(128), 0, stream,
                       x, W1, i1ff);
    hipLaunchKernelGGL(recur2, dim3(BB), dim3(512), 0, stream,
                       i1ff, Wr2T, W2T, W4, b1, b2, br2, b4,
                       Vth1, tau1, Vth2, tau2, tau_out, (float*)d_out);
  } else {
    float* Wr2T = (float*)ws;
    float* W2T  = (float*)(ws + WS_TBL);

    hipLaunchKernelGGL(prep_weights, dim3((513 * 512 + 255) / 256), dim3(256), 0, stream,
                       W2, Wr2, Wr2T, W2T);
    hipLaunchKernelGGL(recur_fb, dim3(BB), dim3(512), 0, stream,
                       x, W1, Wr2T, W2T, W4, b1, b2, br2, b4,
                       Vth1, tau1, Vth2, tau2, tau_out, (float*)d_out);
  }
}

// Round 5
// 2988.193 us; speedup vs baseline: 3.1786x; 3.1694x over previous
//
#include <hip/hip_runtime.h>

// Emulate numpy f32 per-op rounding exactly: no implicit mul+add fusion.
#pragma clang fp contract(off)

typedef unsigned short u16;
typedef unsigned int u32;
typedef unsigned long long u64;

#define BB 512
#define CC 128
#define TT 500
#define NN 512
#define T_TILE 16

#define TBL_BYTES 1050624ull          // 513*512*4
#define CHUNK_ROW_BYTES 1048576ull    // 512*512*4 per timestep
#define ST_ARR_BYTES 1048576ull       // 512*512*4 per state array

// ---------------- prep kernel ----------------
// Transposed weights with a 513th all-zero row (index NN) used as the padding
// target so sparse loops run in groups of 8 branch-free (adding 0.0f is exact).
__global__ void prep_weights(const float* __restrict__ W2, const float* __restrict__ Wr2,
                             float* __restrict__ Wr2T, float* __restrict__ W2T) {
  int i = blockIdx.x * blockDim.x + threadIdx.x;
  if (i < 513 * 512) {
    int k = i >> 9, n = i & 511;
    Wr2T[i] = (k < NN) ? Wr2[n * NN + k] : 0.0f;
    W2T[i]  = (k < NN) ? W2[n * NN + k] : 0.0f;
  }
}

// ---------------- i1ff GEMM (chunked): i1ff[b][tl][n] = chain_c x[b][c][t]*W1[n][c] ----
// Bit-exact: each output is ONE ascending-c fmaf chain starting at 0.
__global__ void __launch_bounds__(128, 3)
gemm_i1ff(const float* __restrict__ x, const float* __restrict__ W1,
          float* __restrict__ i1ff, int tBeg, int tLen) {
  const int b = blockIdx.x;
  const int tl0 = blockIdx.y * T_TILE;   // chunk-local t of tile start
  const int tid = threadIdx.x;

  __shared__ float xs[CC * T_TILE];      // [c][j], 8 KB
  __shared__ float W1L[NN * 9];          // [n][cc], padded pitch 9, 18 KB

  for (int i = tid; i < CC * T_TILE; i += 128) {
    int c = i >> 4, j = i & 15;
    int tl = tl0 + j;
    xs[c * T_TILE + j] = (tl < tLen) ? x[(b * CC + c) * TT + (tBeg + tl)] : 0.0f;
  }

  float acc[4][T_TILE];
#pragma unroll
  for (int r = 0; r < 4; ++r)
#pragma unroll
    for (int j = 0; j < T_TILE; ++j) acc[r][j] = 0.0f;

  for (int cp = 0; cp < CC / 8; ++cp) {
    __syncthreads();  // guards xs stores (cp==0) and previous-panel reads
    for (int i = tid; i < NN * 8; i += 128) {
      int nn = i >> 3, cc = i & 7;
      W1L[nn * 9 + cc] = W1[nn * CC + cp * 8 + cc];
    }
    __syncthreads();
#pragma unroll
    for (int cc = 0; cc < 8; ++cc) {
      const int c = cp * 8 + cc;
      float w0 = W1L[(tid + 0)   * 9 + cc];
      float w1 = W1L[(tid + 128) * 9 + cc];
      float w2 = W1L[(tid + 256) * 9 + cc];
      float w3 = W1L[(tid + 384) * 9 + cc];
#pragma unroll
      for (int j = 0; j < T_TILE; ++j) {
        float xv = xs[c * T_TILE + j];
        acc[0][j] = __builtin_fmaf(xv, w0, acc[0][j]);
        acc[1][j] = __builtin_fmaf(xv, w1, acc[1][j]);
        acc[2][j] = __builtin_fmaf(xv, w2, acc[2][j]);
        acc[3][j] = __builtin_fmaf(xv, w3, acc[3][j]);
      }
    }
  }

#pragma unroll
  for (int j = 0; j < T_TILE; ++j) {
    int tl = tl0 + j;
    if (tl < tLen) {
      float* o = i1ff + ((size_t)b * tLen + tl) * NN;
      o[tid + 0]   = acc[0][j];
      o[tid + 128] = acc[1][j];
      o[tid + 256] = acc[2][j];
      o[tid + 384] = acc[3][j];
    }
  }
}

// ---------------- sparse row-sum (pipelined, bit-exact ascending order) ----------------
template <int PRE>
__device__ __forceinline__ float sparse_sum_pre(const float* __restrict__ mat,
                                                const u16* list, int cnt, int n) {
  if (cnt <= 0) return 0.0f;
  const int ng = (cnt + 7) >> 3;
  const int npre = ng < PRE ? ng : PRE;
  float buf[PRE * 8];
#pragma unroll
  for (int g = 0; g < PRE; ++g) {
    if (g < npre) {
      uint4 q = *(const uint4*)(list + g * 8);
      buf[g * 8 + 0] = mat[(q.x & 0xffff) * NN + n];
      buf[g * 8 + 1] = mat[(q.x >> 16) * NN + n];
      buf[g * 8 + 2] = mat[(q.y & 0xffff) * NN + n];
      buf[g * 8 + 3] = mat[(q.y >> 16) * NN + n];
      buf[g * 8 + 4] = mat[(q.z & 0xffff) * NN + n];
      buf[g * 8 + 5] = mat[(q.z >> 16) * NN + n];
      buf[g * 8 + 6] = mat[(q.w & 0xffff) * NN + n];
      buf[g * 8 + 7] = mat[(q.w >> 16) * NN + n];
    }
  }
  float s = 0.0f;
#pragma unroll
  for (int g = 0; g < PRE; ++g) {
    if (g < npre) {
#pragma unroll
      for (int j = 0; j < 8; ++j) s += buf[g * 8 + j];
    }
  }
  for (int i = PRE * 8; i < cnt; i += 8) {  // rare tail
    uint4 q = *(const uint4*)(list + i);
    float f0 = mat[(q.x & 0xffff) * NN + n];
    float f1 = mat[(q.x >> 16) * NN + n];
    float f2 = mat[(q.y & 0xffff) * NN + n];
    float f3 = mat[(q.y >> 16) * NN + n];
    float f4 = mat[(q.z & 0xffff) * NN + n];
    float f5 = mat[(q.z >> 16) * NN + n];
    float f6 = mat[(q.w & 0xffff) * NN + n];
    float f7 = mat[(q.w >> 16) * NN + n];
    s += f0; s += f1; s += f2; s += f3;
    s += f4; s += f5; s += f6; s += f7;
  }
  return s;
}

__device__ __forceinline__ void build_list(const u64* words, int mybit, int lane,
                                           int wave, int n, u16* slot, int* cnt) {
  int tot = 0, base = 0;
#pragma unroll
  for (int j = 0; j < 8; ++j) {
    int pj = __popcll(words[j]);
    if (j < wave) base += pj;
    tot += pj;
  }
  if (tot) {
    if (mybit) {
      int pos = base + __popcll(words[wave] & ((1ull << lane) - 1ull));
      slot[pos] = (u16)n;
    }
    if (n < 8) slot[tot + n] = (u16)NN;  // pad -> zero row
  }
  if (n == 0) *cnt = tot;
}

// ---------------- chunked recurrent kernel ----------------
__global__ void __launch_bounds__(512, 2)
recur2(const float* __restrict__ i1ff, const float* __restrict__ Wr2T,
       const float* __restrict__ W2T, const float* __restrict__ W4,
       const float* __restrict__ b1, const float* __restrict__ b2,
       const float* __restrict__ br2, const float* __restrict__ b4,
       const float* __restrict__ Vth1, const float* __restrict__ tau1,
       const float* __restrict__ Vth2, const float* __restrict__ tau2,
       const float* __restrict__ tau_out, float* __restrict__ out,
       float* __restrict__ stM1, float* __restrict__ stM2,
       u32* __restrict__ stSC1, u32* __restrict__ stSC2,
       u64* __restrict__ stW, float* __restrict__ stMemo,
       int tBeg, int tLen, int isFirst, int isLast) {
  const int n = threadIdx.x, b = blockIdx.x;
  const int lane = n & 63, wave = n >> 6;

  __shared__ u64 wordsA[8], wordsB[8];
  __shared__ __align__(16) u16 listA[2][528];
  __shared__ __align__(16) u16 listB[2][528];
  __shared__ int cA[2], cB[2];

  float mem1, mem2;
  int sc1, sc2;
  float memo0 = 0.0f, memo1 = 0.0f;
  if (isFirst) {
    mem1 = 0.0f; mem2 = 0.0f; sc1 = 0; sc2 = 0;
    if (n < 8) wordsA[n] = 0ull;
    else if (n < 16) wordsB[n - 8] = 0ull;
  } else {
    mem1 = stM1[b * NN + n]; mem2 = stM2[b * NN + n];
    sc1 = (int)stSC1[b * NN + n]; sc2 = (int)stSC2[b * NN + n];
    if (n < 8) wordsA[n] = stW[b * 16 + n];
    else if (n < 16) wordsB[n - 8] = stW[b * 16 + n];
    if (n == 0) { memo0 = stMemo[b * 2]; memo1 = stMemo[b * 2 + 1]; }
  }
  __syncthreads();
  int sp1 = (int)((wordsA[wave] >> lane) & 1ull);
  int sp2 = (int)((wordsB[wave] >> lane) & 1ull);
  // initial lists into parity slot 0 (tBeg is always even)
  build_list(wordsA, sp1, lane, wave, n, listA[0], &cA[0]);
  build_list(wordsB, sp2, lane, wave, n, listB[0], &cB[0]);
  // first in-loop B0 orders these before use

  const float b1v = b1[n], b2v = b2[n], br2v = br2[n];
  const float t1 = tau1[n], t2 = tau2[n];
  const float v1 = Vth1[n], v2 = Vth2[n];
  const float to0 = tau_out[0], to1 = tau_out[1];
  const float b40 = b4[0], b41 = b4[1];

  const float* ffp = i1ff + (size_t)b * tLen * NN + n;
  float ffcur = ffp[0];

  for (int t = tBeg; t < tBeg + tLen; ++t) {
    const int tt = t - tBeg;
    const int pp = t & 1, qq = pp ^ 1;
    const int ttn = (tt + 1 < tLen) ? tt + 1 : tt;
    float ffnext = ffp[(size_t)ttn * NN];   // issued pre-barrier, used next iter
    __syncthreads();  // B0

    // ---- layer 1: i1 = (x@W1^T + b1) + (sp1@Wr2^T + br2) ----
    float r1 = sparse_sum_pre<5>(Wr2T, listA[pp], cA[pp], n);
    float u1 = ffcur + b1v;
    float w1s = r1 + br2v;
    float i1 = u1 + w1s;
    float a1m = t1 * mem1;
    a1m = sp1 ? 0.0f : a1m;
    float m1 = a1m + i1;
    mem1 = m1;
    const int s1 = (m1 - v1) > 0.0f ? 1 : 0;
    u64 ba = __ballot(s1 != 0);
    if (lane == 0) wordsA[wave] = ba;
    __syncthreads();  // B1

    build_list(wordsA, s1, lane, wave, n, listA[qq], &cA[qq]);
    __syncthreads();  // B1b

    // ---- layer 2: i2 = (s1@W2^T + b2) + (sp2@Wr2^T + br2) ----
    float ff = sparse_sum_pre<5>(W2T, listA[qq], cA[qq], n);
    float u2 = ff + b2v;
    float r2 = sparse_sum_pre<5>(Wr2T, listB[pp], cB[pp], n);
    float w2s = r2 + br2v;
    float i2 = u2 + w2s;
    float a2m = t2 * mem2;
    a2m = sp2 ? 0.0f : a2m;
    float m2 = a2m + i2;
    mem2 = m2;
    const int s2 = (m2 - v2) > 0.0f ? 1 : 0;
    u64 bb = __ballot(s2 != 0);
    if (lane == 0) wordsB[wave] = bb;
    sp1 = s1; sp2 = s2; sc1 += s1; sc2 += s2;
    ffcur = ffnext;
    __syncthreads();  // B2

    build_list(wordsB, s2, lane, wave, n, listB[qq], &cB[qq]);

    // ---- readout: memo = (tau_out*memo) + ((s2@W4^T) + b4) ----
    if (n == 0) {
      float a0 = 0.0f, a1 = 0.0f;
#pragma unroll
      for (int w = 0; w < 8; ++w) {
        u64 m = wordsB[w];
        while (m) {
          int k = (w << 6) + __builtin_ctzll(m);
          m &= m - 1ull;
          a0 += W4[k];
          a1 += W4[NN + k];
        }
      }
      float z0 = to0 * memo0;
      float z1 = to1 * memo1;
      memo0 = z0 + (a0 + b40);
      memo1 = z1 + (a1 + b41);
      out[(b * 2 + 0) * TT + t] = memo0;
      out[(b * 2 + 1) * TT + t] = memo1;
    }
  }

  if (isLast) {
    out[BB * 2 * TT + b * NN + n]           = (float)sc1 / 500.0f;
    out[BB * 2 * TT + BB * NN + b * NN + n] = (float)sc2 / 500.0f;
  } else {
    __syncthreads();
    stM1[b * NN + n] = mem1; stM2[b * NN + n] = mem2;
    stSC1[b * NN + n] = (u32)sc1; stSC2[b * NN + n] = (u32)sc2;
    if (n < 8) stW[b * 16 + n] = wordsA[n];
    else if (n < 16) stW[b * 16 + n] = wordsB[n - 8];
    if (n == 0) { stMemo[b * 2] = memo0; stMemo[b * 2 + 1] = memo1; }
  }
}

// ---------------- fallback monolithic kernel (tiny ws): no-spill GEMV ----------------
__global__ void __launch_bounds__(512) __attribute__((amdgpu_waves_per_eu(2, 2)))
recur_fb(const float* __restrict__ x, const float* __restrict__ W1,
         const float* __restrict__ Wr2T, const float* __restrict__ W2T,
         const float* __restrict__ W4,
         const float* __restrict__ b1, const float* __restrict__ b2,
         const float* __restrict__ br2, const float* __restrict__ b4,
         const float* __restrict__ Vth1, const float* __restrict__ tau1,
         const float* __restrict__ Vth2, const float* __restrict__ tau2,
         const float* __restrict__ tau_out, float* __restrict__ out) {
  const int n = threadIdx.x, b = blockIdx.x;
  const int lane = n & 63, wave = n >> 6;

  __shared__ float xs[CC];
  __shared__ u64 wordsA[8], wordsB[8];
  __shared__ __align__(16) u16 listA[2][528];
  __shared__ __align__(16) u16 listB[2][528];
  __shared__ int cA[2], cB[2];

  float w1r[CC];  // fits: waves_per_eu(2,2) -> 256-VGPR budget, no spill
  {
    const float4* wp = (const float4*)(W1 + n * CC);
#pragma unroll
    for (int i = 0; i < CC / 4; ++i) {
      float4 q = wp[i];
      w1r[i * 4 + 0] = q.x; w1r[i * 4 + 1] = q.y;
      w1r[i * 4 + 2] = q.z; w1r[i * 4 + 3] = q.w;
    }
  }

  float mem1 = 0.0f, mem2 = 0.0f;
  const float b1v = b1[n], b2v = b2[n], br2v = br2[n];
  const float t1 = tau1[n], t2 = tau2[n];
  const float v1 = Vth1[n], v2 = Vth2[n];
  const float to0 = tau_out[0], to1 = tau_out[1];
  const float b40 = b4[0], b41 = b4[1];
  int sp1 = 0, sp2 = 0, sc1 = 0, sc2 = 0;
  float memo0 = 0.0f, memo1 = 0.0f;

  if (n == 0) { cA[0] = 0; cB[0] = 0; }

  for (int t = 0; t < TT; ++t) {
    const int pp = t & 1, qq = pp ^ 1;
    if (n < CC) xs[n] = x[(b * CC + n) * TT + t];
    __syncthreads();

    float acc = 0.0f;
#pragma unroll
    for (int c = 0; c < CC; ++c) acc = __builtin_fmaf(xs[c], w1r[c], acc);
    float u1 = acc + b1v;
    float r1 = sparse_sum_pre<6>(Wr2T, listA[pp], cA[pp], n);
    float w1s = r1 + br2v;
    float i1 = u1 + w1s;
    float a1m = t1 * mem1;
    a1m = sp1 ? 0.0f : a1m;
    float m1 = a1m + i1;
    mem1 = m1;
    const int s1 = (m1 - v1) > 0.0f ? 1 : 0;
    u64 ba = __ballot(s1 != 0);
    if (lane == 0) wordsA[wave] = ba;
    __syncthreads();

    build_list(wordsA, s1, lane, wave, n, listA[qq], &cA[qq]);
    __syncthreads();

    float ff = sparse_sum_pre<6>(W2T, listA[qq], cA[qq], n);
    float u2 = ff + b2v;
    float r2 = sparse_sum_pre<6>(Wr2T, listB[pp], cB[pp], n);
    float w2s = r2 + br2v;
    float i2 = u2 + w2s;
    float a2m = t2 * mem2;
    a2m = sp2 ? 0.0f : a2m;
    float m2 = a2m + i2;
    mem2 = m2;
    const int s2 = (m2 - v2) > 0.0f ? 1 : 0;
    u64 bb = __ballot(s2 != 0);
    if (lane == 0) wordsB[wave] = bb;
    sp1 = s1; sp2 = s2; sc1 += s1; sc2 += s2;
    __syncthreads();

    build_list(wordsB, s2, lane, wave, n, listB[qq], &cB[qq]);

    if (n == 0) {
      float a0 = 0.0f, a1 = 0.0f;
#pragma unroll
      for (int w = 0; w < 8; ++w) {
        u64 m = wordsB[w];
        while (m) {
          int k = (w << 6) + __builtin_ctzll(m);
          m &= m - 1ull;
          a0 += W4[k];
          a1 += W4[NN + k];
        }
      }
      float z0 = to0 * memo0;
      float z1 = to1 * memo1;
      memo0 = z0 + (a0 + b40);
      memo1 = z1 + (a1 + b41);
      out[(b * 2 + 0) * TT + t] = memo0;
      out[(b * 2 + 1) * TT + t] = memo1;
    }
  }

  out[BB * 2 * TT + b * NN + n]           = (float)sc1 / 500.0f;
  out[BB * 2 * TT + BB * NN + b * NN + n] = (float)sc2 / 500.0f;
}

// ---------------- launcher ----------------
extern "C" void kernel_launch(void* const* d_in, const int* in_sizes, int n_in,
                              void* d_out, int out_size, void* d_ws, size_t ws_size,
                              hipStream_t stream) {
  (void)in_sizes; (void)n_in; (void)out_size;
  const float* x    = (const float*)d_in[0];
  const float* W1   = (const float*)d_in[1];
  const float* b1   = (const float*)d_in[2];
  const float* W2   = (const float*)d_in[3];
  const float* b2   = (const float*)d_in[4];
  const float* Wr2  = (const float*)d_in[5];
  const float* br2  = (const float*)d_in[6];
  // d_in[7..10] = W3,b3,Wr3,br3: dead code w.r.t. outputs — skipped
  const float* W4   = (const float*)d_in[11];
  const float* b4   = (const float*)d_in[12];
  const float* Vth1 = (const float*)d_in[13];
  const float* tau1 = (const float*)d_in[14];
  const float* Vth2 = (const float*)d_in[15];
  const float* tau2 = (const float*)d_in[16];
  const float* tau_out = (const float*)d_in[19];

  char* ws = (char*)d_ws;

  // aux: 2 weight tables + 4 state arrays + ballot words + memo
  const size_t aux = 2 * TBL_BYTES + 4 * ST_ARR_BYTES + 512ull * 16 * 8 + 512ull * 2 * 4;

  int chunkT = 0;
  if (ws_size > aux) {
    long long ct = (long long)((ws_size - aux) / CHUNK_ROW_BYTES);
    if (ct > TT) ct = TT;
    ct &= ~1LL;  // even start for every chunk (list parity)
    if (ct >= 16) chunkT = (int)ct;
  }

  if (chunkT >= 16) {
    char* p = ws;
    float* i1ff = (float*)p;  p += (size_t)chunkT * CHUNK_ROW_BYTES;
    float* Wr2T = (float*)p;  p += TBL_BYTES;
    float* W2T  = (float*)p;  p += TBL_BYTES;
    float* stM1 = (float*)p;  p += ST_ARR_BYTES;
    float* stM2 = (float*)p;  p += ST_ARR_BYTES;
    u32* stSC1  = (u32*)p;    p += ST_ARR_BYTES;
    u32* stSC2  = (u32*)p;    p += ST_ARR_BYTES;
    u64* stW    = (u64*)p;    p += 512ull * 16 * 8;
    float* stMemo = (float*)p;

    hipLaunchKernelGGL(prep_weights, dim3((513 * 512 + 255) / 256), dim3(256), 0, stream,
                       W2, Wr2, Wr2T, W2T);
    for (int t0 = 0; t0 < TT; t0 += chunkT) {
      int len = (TT - t0 < chunkT) ? (TT - t0) : chunkT;
      hipLaunchKernelGGL(gemm_i1ff, dim3(BB, (len + T_TILE - 1) / T_TILE), dim3(128), 0,
                         stream, x, W1, i1ff, t0, len);
      hipLaunchKernelGGL(recur2, dim3(BB), dim3(512), 0, stream,
                         i1ff, Wr2T, W2T, W4, b1, b2, br2, b4,
                         Vth1, tau1, Vth2, tau2, tau_out, (float*)d_out,
                         stM1, stM2, stSC1, stSC2, stW, stMemo,
                         t0, len, (t0 == 0) ? 1 : 0, (t0 + len == TT) ? 1 : 0);
    }
  } else {
    float* Wr2T = (float*)ws;
    float* W2T  = (float*)(ws + TBL_BYTES);
    hipLaunchKernelGGL(prep_weights, dim3((513 * 512 + 255) / 256), dim3(256), 0, stream,
                       W2, Wr2, Wr2T, W2T);
    hipLaunchKernelGGL(recur_fb, dim3(BB), dim3(512), 0, stream,
                       x, W1, Wr2T, W2T, W4, b1, b2, br2, b4,
                       Vth1, tau1, Vth2, tau2, tau_out, (float*)d_out);
  }
}

// Round 6
// 2779.524 us; speedup vs baseline: 3.4173x; 1.0751x over previous
//
#include <hip/hip_runtime.h>

// Emulate numpy f32 per-op rounding exactly: no implicit mul+add fusion.
#pragma clang fp contract(off)

typedef unsigned short u16;
typedef unsigned int u32;
typedef unsigned long long u64;

#define BB 512
#define CC 128
#define TT 500
#define NN 512
#define T_TILE 32

#define TBL_BYTES 1050624ull          // 513*512*4
#define CHUNK_ROW_BYTES 1048576ull    // 512*512*4 per timestep
#define ST_ARR_BYTES 1048576ull       // 512*512*4 per state array
#define PAD_OFF (512u << 11)          // byte offset of the all-zero row

// ---------------- prep kernel ----------------
// Transposed weights with a 513th all-zero row used as the padding target so
// sparse loops run in groups of 8 branch-free (adding 0.0f is exact).
__global__ void prep_weights(const float* __restrict__ W2, const float* __restrict__ Wr2,
                             float* __restrict__ Wr2T, float* __restrict__ W2T) {
  int i = blockIdx.x * blockDim.x + threadIdx.x;
  if (i < 513 * 512) {
    int k = i >> 9, n = i & 511;
    Wr2T[i] = (k < NN) ? Wr2[n * NN + k] : 0.0f;
    W2T[i]  = (k < NN) ? W2[n * NN + k] : 0.0f;
  }
}

// ---------------- i1ff GEMM (chunked): i1ff[b][tl][n] = chain_c x[b][c][t]*W1[n][c] ----
// Bit-exact: each output is ONE ascending-c fmaf chain starting at 0.
__global__ void __launch_bounds__(128, 2)
gemm_i1ff(const float* __restrict__ x, const float* __restrict__ W1,
          float* __restrict__ i1ff, int tBeg, int tLen) {
  const int b = blockIdx.x;
  const int tl0 = blockIdx.y * T_TILE;   // chunk-local t of tile start
  const int tid = threadIdx.x;

  __shared__ float xs[CC * T_TILE];      // [c][j], 16 KB
  __shared__ float W1L[NN * 9];          // [n][cc], padded pitch 9 (odd -> conflict-free), 18 KB

  // stage x tile: consecutive threads -> consecutive t (coalesced)
  for (int i = tid; i < CC * T_TILE; i += 128) {
    int c = i >> 5, j = i & 31;
    int tl = tl0 + j;
    xs[c * T_TILE + j] = (tl < tLen) ? x[(b * CC + c) * TT + (tBeg + tl)] : 0.0f;
  }

  float acc[4][T_TILE];
#pragma unroll
  for (int r = 0; r < 4; ++r)
#pragma unroll
    for (int j = 0; j < T_TILE; ++j) acc[r][j] = 0.0f;

  for (int cp = 0; cp < CC / 8; ++cp) {
    __syncthreads();  // guards xs stores (cp==0) and previous-panel reads
    for (int i = tid; i < NN * 8; i += 128) {
      int nn = i >> 3, cc = i & 7;
      W1L[nn * 9 + cc] = W1[nn * CC + cp * 8 + cc];
    }
    __syncthreads();
#pragma unroll
    for (int cc = 0; cc < 8; ++cc) {
      const int c = cp * 8 + cc;
      float w0 = W1L[(tid + 0)   * 9 + cc];
      float w1 = W1L[(tid + 128) * 9 + cc];
      float w2 = W1L[(tid + 256) * 9 + cc];
      float w3 = W1L[(tid + 384) * 9 + cc];
#pragma unroll
      for (int j = 0; j < T_TILE; ++j) {
        float xv = xs[c * T_TILE + j];   // broadcast (conflict-free)
        acc[0][j] = __builtin_fmaf(xv, w0, acc[0][j]);
        acc[1][j] = __builtin_fmaf(xv, w1, acc[1][j]);
        acc[2][j] = __builtin_fmaf(xv, w2, acc[2][j]);
        acc[3][j] = __builtin_fmaf(xv, w3, acc[3][j]);
      }
    }
  }

#pragma unroll
  for (int j = 0; j < T_TILE; ++j) {
    int tl = tl0 + j;
    if (tl < tLen) {
      float* o = i1ff + ((size_t)b * tLen + tl) * NN;
      o[tid + 0]   = acc[0][j];
      o[tid + 128] = acc[1][j];
      o[tid + 256] = acc[2][j];
      o[tid + 384] = acc[3][j];
    }
  }
}

// ---------------- sparse row-sum (pre-scaled u32 byte offsets, bit-exact order) ----
// list entries are k*2048 byte offsets (pad = zero row). Per element:
// v_add_u32 (off+n4) + saddr global_load + v_add_f32.  Strict ascending chain.
template <int PRE>
__device__ __forceinline__ float sparse_sum_pre(const float* __restrict__ mat,
                                                const u32* list, int cnt, u32 n4) {
  if (cnt <= 0) return 0.0f;
  const char* base = (const char*)mat;
  const int ng = (cnt + 7) >> 3;
  const int npre = ng < PRE ? ng : PRE;
  float buf[PRE * 8];
#pragma unroll
  for (int g = 0; g < PRE; ++g) {
    if (g < npre) {
      uint4 qa = *(const uint4*)(list + g * 8);
      uint4 qb = *(const uint4*)(list + g * 8 + 4);
      buf[g * 8 + 0] = *(const float*)(base + (qa.x + n4));
      buf[g * 8 + 1] = *(const float*)(base + (qa.y + n4));
      buf[g * 8 + 2] = *(const float*)(base + (qa.z + n4));
      buf[g * 8 + 3] = *(const float*)(base + (qa.w + n4));
      buf[g * 8 + 4] = *(const float*)(base + (qb.x + n4));
      buf[g * 8 + 5] = *(const float*)(base + (qb.y + n4));
      buf[g * 8 + 6] = *(const float*)(base + (qb.z + n4));
      buf[g * 8 + 7] = *(const float*)(base + (qb.w + n4));
    }
  }
  float s = 0.0f;
#pragma unroll
  for (int g = 0; g < PRE; ++g) {
    if (g < npre) {
#pragma unroll
      for (int j = 0; j < 8; ++j) s += buf[g * 8 + j];
    }
  }
  for (int i = PRE * 8; i < cnt; i += 8) {  // rare tail
    uint4 qa = *(const uint4*)(list + i);
    uint4 qb = *(const uint4*)(list + i + 4);
    float f0 = *(const float*)(base + (qa.x + n4));
    float f1 = *(const float*)(base + (qa.y + n4));
    float f2 = *(const float*)(base + (qa.z + n4));
    float f3 = *(const float*)(base + (qa.w + n4));
    float f4 = *(const float*)(base + (qb.x + n4));
    float f5 = *(const float*)(base + (qb.y + n4));
    float f6 = *(const float*)(base + (qb.z + n4));
    float f7 = *(const float*)(base + (qb.w + n4));
    s += f0; s += f1; s += f2; s += f3;
    s += f4; s += f5; s += f6; s += f7;
  }
  return s;
}

// position via v_mbcnt (2 VALU); word totals via readfirstlane -> s_bcnt1 (SALU).
__device__ __forceinline__ void build_list(const u64* words, int mybit, int wave,
                                           u32 nOff, int n, u32* slot, int* cnt) {
  int tot = 0, base = 0;
#pragma unroll
  for (int j = 0; j < 8; ++j) {
    u64 w = words[j];
    u32 lo = __builtin_amdgcn_readfirstlane((u32)w);
    u32 hi = __builtin_amdgcn_readfirstlane((u32)(w >> 32));
    int pj = __popc(lo) + __popc(hi);
    if (j < wave) base += pj;
    tot += pj;
  }
  if (tot) {
    if (mybit) {
      u64 w = words[wave];
      int below = __builtin_amdgcn_mbcnt_hi((u32)(w >> 32),
                    __builtin_amdgcn_mbcnt_lo((u32)w, 0u));
      slot[base + below] = nOff;
    }
    if (n < 8) slot[tot + n] = PAD_OFF;  // pad -> zero row
  }
  if (n == 0) *cnt = tot;
}

// ---------------- chunked recurrent kernel ----------------
__global__ void __launch_bounds__(512, 2)
recur2(const float* __restrict__ i1ff, const float* __restrict__ Wr2T,
       const float* __restrict__ W2T, const float* __restrict__ W4,
       const float* __restrict__ b1, const float* __restrict__ b2,
       const float* __restrict__ br2, const float* __restrict__ b4,
       const float* __restrict__ Vth1, const float* __restrict__ tau1,
       const float* __restrict__ Vth2, const float* __restrict__ tau2,
       const float* __restrict__ tau_out, float* __restrict__ out,
       float* __restrict__ stM1, float* __restrict__ stM2,
       u32* __restrict__ stSC1, u32* __restrict__ stSC2,
       u64* __restrict__ stW, float* __restrict__ stMemo,
       int tBeg, int tLen, int isFirst, int isLast) {
  const int n = threadIdx.x, b = blockIdx.x;
  const int lane = n & 63, wave = n >> 6;
  const u32 n4 = (u32)(n << 2);
  const u32 nOff = (u32)(n << 11);

  __shared__ u64 wordsA[8], wordsB[8];
  __shared__ __align__(16) u32 listA[2][520];
  __shared__ __align__(16) u32 listB[2][520];
  __shared__ int cA[2], cB[2];

  float mem1, mem2;
  int sc1, sc2;
  float memo0 = 0.0f, memo1 = 0.0f;
  if (isFirst) {
    mem1 = 0.0f; mem2 = 0.0f; sc1 = 0; sc2 = 0;
    if (n < 8) wordsA[n] = 0ull;
    else if (n < 16) wordsB[n - 8] = 0ull;
  } else {
    mem1 = stM1[b * NN + n]; mem2 = stM2[b * NN + n];
    sc1 = (int)stSC1[b * NN + n]; sc2 = (int)stSC2[b * NN + n];
    if (n < 8) wordsA[n] = stW[b * 16 + n];
    else if (n < 16) wordsB[n - 8] = stW[b * 16 + n];
    if (n == 0) { memo0 = stMemo[b * 2]; memo1 = stMemo[b * 2 + 1]; }
  }
  __syncthreads();
  int sp1 = (int)((wordsA[wave] >> lane) & 1ull);
  int sp2 = (int)((wordsB[wave] >> lane) & 1ull);
  // initial lists into parity slot 0 (tBeg is always even)
  build_list(wordsA, sp1, wave, nOff, n, listA[0], &cA[0]);
  build_list(wordsB, sp2, wave, nOff, n, listB[0], &cB[0]);
  // first in-loop B0 orders these before use

  const float b1v = b1[n], b2v = b2[n], br2v = br2[n];
  const float t1 = tau1[n], t2 = tau2[n];
  const float v1 = Vth1[n], v2 = Vth2[n];
  const float to0 = tau_out[0], to1 = tau_out[1];
  const float b40 = b4[0], b41 = b4[1];

  const float* ffp = i1ff + (size_t)b * tLen * NN + n;
  float ffcur = ffp[0];

  for (int t = tBeg; t < tBeg + tLen; ++t) {
    const int tt = t - tBeg;
    const int pp = t & 1, qq = pp ^ 1;
    const int ttn = (tt + 1 < tLen) ? tt + 1 : tt;
    float ffnext = ffp[(size_t)ttn * NN];   // issued pre-barrier, used next iter
    __syncthreads();  // B0

    // ---- layer 1: i1 = (x@W1^T + b1) + (sp1@Wr2^T + br2) ----
    float r1 = sparse_sum_pre<6>(Wr2T, listA[pp], cA[pp], n4);
    float u1 = ffcur + b1v;
    float w1s = r1 + br2v;
    float i1 = u1 + w1s;
    float a1m = t1 * mem1;
    a1m = sp1 ? 0.0f : a1m;
    float m1 = a1m + i1;
    mem1 = m1;
    const int s1 = (m1 - v1) > 0.0f ? 1 : 0;
    u64 ba = __ballot(s1 != 0);
    if (lane == 0) wordsA[wave] = ba;
    __syncthreads();  // B1

    build_list(wordsA, s1, wave, nOff, n, listA[qq], &cA[qq]);
    __syncthreads();  // B1b

    // ---- layer 2: i2 = (s1@W2^T + b2) + (sp2@Wr2^T + br2) ----
    float ff = sparse_sum_pre<6>(W2T, listA[qq], cA[qq], n4);
    float u2 = ff + b2v;
    float r2 = sparse_sum_pre<6>(Wr2T, listB[pp], cB[pp], n4);
    float w2s = r2 + br2v;
    float i2 = u2 + w2s;
    float a2m = t2 * mem2;
    a2m = sp2 ? 0.0f : a2m;
    float m2 = a2m + i2;
    mem2 = m2;
    const int s2 = (m2 - v2) > 0.0f ? 1 : 0;
    u64 bb = __ballot(s2 != 0);
    if (lane == 0) wordsB[wave] = bb;
    sp1 = s1; sp2 = s2; sc1 += s1; sc2 += s2;
    ffcur = ffnext;
    __syncthreads();  // B2

    build_list(wordsB, s2, wave, nOff, n, listB[qq], &cB[qq]);

    // ---- readout: memo = (tau_out*memo) + ((s2@W4^T) + b4) ----
    if (n == 0) {
      float a0 = 0.0f, a1 = 0.0f;  // ascending-k f32 chains (s2 ~never fires)
#pragma unroll
      for (int w = 0; w < 8; ++w) {
        u64 m = wordsB[w];
        while (m) {
          int k = (w << 6) + __builtin_ctzll(m);
          m &= m - 1ull;
          a0 += W4[k];
          a1 += W4[NN + k];
        }
      }
      float z0 = to0 * memo0;
      float z1 = to1 * memo1;
      memo0 = z0 + (a0 + b40);
      memo1 = z1 + (a1 + b41);
      out[(b * 2 + 0) * TT + t] = memo0;
      out[(b * 2 + 1) * TT + t] = memo1;
    }
  }

  if (isLast) {
    out[BB * 2 * TT + b * NN + n]           = (float)sc1 / 500.0f;
    out[BB * 2 * TT + BB * NN + b * NN + n] = (float)sc2 / 500.0f;
  } else {
    __syncthreads();
    stM1[b * NN + n] = mem1; stM2[b * NN + n] = mem2;
    stSC1[b * NN + n] = (u32)sc1; stSC2[b * NN + n] = (u32)sc2;
    if (n < 8) stW[b * 16 + n] = wordsA[n];
    else if (n < 16) stW[b * 16 + n] = wordsB[n - 8];
    if (n == 0) { stMemo[b * 2] = memo0; stMemo[b * 2 + 1] = memo1; }
  }
}

// ---------------- fallback monolithic kernel (tiny ws): no-spill GEMV ----------------
__global__ void __launch_bounds__(512) __attribute__((amdgpu_waves_per_eu(2, 2)))
recur_fb(const float* __restrict__ x, const float* __restrict__ W1,
         const float* __restrict__ Wr2T, const float* __restrict__ W2T,
         const float* __restrict__ W4,
         const float* __restrict__ b1, const float* __restrict__ b2,
         const float* __restrict__ br2, const float* __restrict__ b4,
         const float* __restrict__ Vth1, const float* __restrict__ tau1,
         const float* __restrict__ Vth2, const float* __restrict__ tau2,
         const float* __restrict__ tau_out, float* __restrict__ out) {
  const int n = threadIdx.x, b = blockIdx.x;
  const int lane = n & 63, wave = n >> 6;
  const u32 n4 = (u32)(n << 2);
  const u32 nOff = (u32)(n << 11);

  __shared__ float xs[CC];
  __shared__ u64 wordsA[8], wordsB[8];
  __shared__ __align__(16) u32 listA[2][520];
  __shared__ __align__(16) u32 listB[2][520];
  __shared__ int cA[2], cB[2];

  float w1r[CC];  // fits: waves_per_eu(2,2) -> 256-VGPR budget, no spill
  {
    const float4* wp = (const float4*)(W1 + n * CC);
#pragma unroll
    for (int i = 0; i < CC / 4; ++i) {
      float4 q = wp[i];
      w1r[i * 4 + 0] = q.x; w1r[i * 4 + 1] = q.y;
      w1r[i * 4 + 2] = q.z; w1r[i * 4 + 3] = q.w;
    }
  }

  float mem1 = 0.0f, mem2 = 0.0f;
  const float b1v = b1[n], b2v = b2[n], br2v = br2[n];
  const float t1 = tau1[n], t2 = tau2[n];
  const float v1 = Vth1[n], v2 = Vth2[n];
  const float to0 = tau_out[0], to1 = tau_out[1];
  const float b40 = b4[0], b41 = b4[1];
  int sp1 = 0, sp2 = 0, sc1 = 0, sc2 = 0;
  float memo0 = 0.0f, memo1 = 0.0f;

  if (n == 0) { cA[0] = 0; cB[0] = 0; }

  for (int t = 0; t < TT; ++t) {
    const int pp = t & 1, qq = pp ^ 1;
    if (n < CC) xs[n] = x[(b * CC + n) * TT + t];
    __syncthreads();

    float acc = 0.0f;
#pragma unroll
    for (int c = 0; c < CC; ++c) acc = __builtin_fmaf(xs[c], w1r[c], acc);
    float u1 = acc + b1v;
    float r1 = sparse_sum_pre<6>(Wr2T, listA[pp], cA[pp], n4);
    float w1s = r1 + br2v;
    float i1 = u1 + w1s;
    float a1m = t1 * mem1;
    a1m = sp1 ? 0.0f : a1m;
    float m1 = a1m + i1;
    mem1 = m1;
    const int s1 = (m1 - v1) > 0.0f ? 1 : 0;
    u64 ba = __ballot(s1 != 0);
    if (lane == 0) wordsA[wave] = ba;
    __syncthreads();

    build_list(wordsA, s1, wave, nOff, n, listA[qq], &cA[qq]);
    __syncthreads();

    float ff = sparse_sum_pre<6>(W2T, listA[qq], cA[qq], n4);
    float u2 = ff + b2v;
    float r2 = sparse_sum_pre<6>(Wr2T, listB[pp], cB[pp], n4);
    float w2s = r2 + br2v;
    float i2 = u2 + w2s;
    float a2m = t2 * mem2;
    a2m = sp2 ? 0.0f : a2m;
    float m2 = a2m + i2;
    mem2 = m2;
    const int s2 = (m2 - v2) > 0.0f ? 1 : 0;
    u64 bb = __ballot(s2 != 0);
    if (lane == 0) wordsB[wave] = bb;
    sp1 = s1; sp2 = s2; sc1 += s1; sc2 += s2;
    __syncthreads();

    build_list(wordsB, s2, wave, nOff, n, listB[qq], &cB[qq]);

    if (n == 0) {
      float a0 = 0.0f, a1 = 0.0f;
#pragma unroll
      for (int w = 0; w < 8; ++w) {
        u64 m = wordsB[w];
        while (m) {
          int k = (w << 6) + __builtin_ctzll(m);
          m &= m - 1ull;
          a0 += W4[k];
          a1 += W4[NN + k];
        }
      }
      float z0 = to0 * memo0;
      float z1 = to1 * memo1;
      memo0 = z0 + (a0 + b40);
      memo1 = z1 + (a1 + b41);
      out[(b * 2 + 0) * TT + t] = memo0;
      out[(b * 2 + 1) * TT + t] = memo1;
    }
  }

  out[BB * 2 * TT + b * NN + n]           = (float)sc1 / 500.0f;
  out[BB * 2 * TT + BB * NN + b * NN + n] = (float)sc2 / 500.0f;
}

// ---------------- launcher ----------------
extern "C" void kernel_launch(void* const* d_in, const int* in_sizes, int n_in,
                              void* d_out, int out_size, void* d_ws, size_t ws_size,
                              hipStream_t stream) {
  (void)in_sizes; (void)n_in; (void)out_size;
  const float* x    = (const float*)d_in[0];
  const float* W1   = (const float*)d_in[1];
  const float* b1   = (const float*)d_in[2];
  const float* W2   = (const float*)d_in[3];
  const float* b2   = (const float*)d_in[4];
  const float* Wr2  = (const float*)d_in[5];
  const float* br2  = (const float*)d_in[6];
  // d_in[7..10] = W3,b3,Wr3,br3: dead code w.r.t. outputs — skipped
  const float* W4   = (const float*)d_in[11];
  const float* b4   = (const float*)d_in[12];
  const float* Vth1 = (const float*)d_in[13];
  const float* tau1 = (const float*)d_in[14];
  const float* Vth2 = (const float*)d_in[15];
  const float* tau2 = (const float*)d_in[16];
  const float* tau_out = (const float*)d_in[19];

  char* ws = (char*)d_ws;

  // aux: 2 weight tables + 4 state arrays + ballot words + memo
  const size_t aux = 2 * TBL_BYTES + 4 * ST_ARR_BYTES + 512ull * 16 * 8 + 512ull * 2 * 4;

  int chunkT = 0;
  if (ws_size > aux) {
    long long ct = (long long)((ws_size - aux) / CHUNK_ROW_BYTES);
    if (ct > TT) ct = TT;
    ct &= ~1LL;  // even start for every chunk (list parity)
    if (ct >= 16) chunkT = (int)ct;
  }

  if (chunkT >= 16) {
    char* p = ws;
    float* i1ff = (float*)p;  p += (size_t)chunkT * CHUNK_ROW_BYTES;
    float* Wr2T = (float*)p;  p += TBL_BYTES;
    float* W2T  = (float*)p;  p += TBL_BYTES;
    float* stM1 = (float*)p;  p += ST_ARR_BYTES;
    float* stM2 = (float*)p;  p += ST_ARR_BYTES;
    u32* stSC1  = (u32*)p;    p += ST_ARR_BYTES;
    u32* stSC2  = (u32*)p;    p += ST_ARR_BYTES;
    u64* stW    = (u64*)p;    p += 512ull * 16 * 8;
    float* stMemo = (float*)p;

    hipLaunchKernelGGL(prep_weights, dim3((513 * 512 + 255) / 256), dim3(256), 0, stream,
                       W2, Wr2, Wr2T, W2T);
    for (int t0 = 0; t0 < TT; t0 += chunkT) {
      int len = (TT - t0 < chunkT) ? (TT - t0) : chunkT;
      hipLaunchKernelGGL(gemm_i1ff, dim3(BB, (len + T_TILE - 1) / T_TILE), dim3(128), 0,
                         stream, x, W1, i1ff, t0, len);
      hipLaunchKernelGGL(recur2, dim3(BB), dim3(512), 0, stream,
                         i1ff, Wr2T, W2T, W4, b1, b2, br2, b4,
                         Vth1, tau1, Vth2, tau2, tau_out, (float*)d_out,
                         stM1, stM2, stSC1, stSC2, stW, stMemo,
                         t0, len, (t0 == 0) ? 1 : 0, (t0 + len == TT) ? 1 : 0);
    }
  } else {
    float* Wr2T = (float*)ws;
    float* W2T  = (float*)(ws + TBL_BYTES);
    hipLaunchKernelGGL(prep_weights, dim3((513 * 512 + 255) / 256), dim3(256), 0, stream,
                       W2, Wr2, Wr2T, W2T);
    hipLaunchKernelGGL(recur_fb, dim3(BB), dim3(512), 0, stream,
                       x, W1, Wr2T, W2T, W4, b1, b2, br2, b4,
                       Vth1, tau1, Vth2, tau2, tau_out, (float*)d_out);
  }
}